// Round 4
// baseline (250.641 us; speedup 1.0000x reference)
//
#include <hip/hip_runtime.h>
#include <hip/hip_bf16.h>

// MHA: B=2 S=2048 D=768 H=12 DK=64. fp32 in/out; bf16 MFMA internally.
#define B_  2
#define S_  2048
#define D_  768
#define H_  12
#define DK_ 64
#define NX_ (B_*S_*D_)      // 3145728 activation elements
#define NW_ (D_*D_)         // 589824 weight elements
#define NR_ (B_*H_*S_)      // 49152 attention rows
#define CSC 0.18033688011112042f   // 0.125 * log2(e), baked into wq/bq

typedef __attribute__((ext_vector_type(8))) short  bf16x8;
typedef __attribute__((ext_vector_type(4))) float  f32x4;

__device__ __forceinline__ unsigned short f2bf(float f) {
    unsigned int u = __float_as_uint(f);
    u += 0x7fffu + ((u >> 16) & 1u);   // RNE
    return (unsigned short)(u >> 16);
}

// pack two fp32 -> two bf16 (RNE-ish: +0x8000 then take hi16) in 3 VALU ops
__device__ __forceinline__ unsigned pack_bf2(float a, float b) {
    const unsigned ua = __float_as_uint(a) + 0x8000u;
    const unsigned ub = __float_as_uint(b) + 0x8000u;
    return __builtin_amdgcn_perm(ub, ua, 0x07060302u);  // lo16=a.hi, hi16=b.hi
}

__device__ __forceinline__ void async_cp16(const unsigned short* g,
                                           const unsigned short* lds_uniform_base) {
    __builtin_amdgcn_global_load_lds(
        (const __attribute__((address_space(1))) unsigned int*)(uintptr_t)g,
        (__attribute__((address_space(3))) unsigned int*)(unsigned int)(uintptr_t)lds_uniform_base,
        16, 0, 0);
}

// ---------------------------------------------------------------------------
// Weight cvt fp32 -> bf16, xor-swizzled per 64-el k-block: group g8 stored at
// g8 ^ (n&7). wq (widx 0) pre-scaled by CSC (folds softmax scale into Q).
// ---------------------------------------------------------------------------
__global__ __launch_bounds__(256) void cvt_w(const float* __restrict__ w0,
                                             const float* __restrict__ w1,
                                             const float* __restrict__ w2,
                                             const float* __restrict__ w3,
                                             unsigned short* __restrict__ dst) {
    const float* src[4] = {w0, w1, w2, w3};
    const int widx = blockIdx.y;
    const float zs = (widx == 0) ? CSC : 1.0f;
    const int idx  = blockIdx.x * 256 + threadIdx.x;   // 73728 per weight
    const int n = idx / 96;
    const int g = idx % 96;
    const float4 f0 = *(const float4*)(src[widx] + (long)n * D_ + g * 8);
    const float4 f1 = *(const float4*)(src[widx] + (long)n * D_ + g * 8 + 4);
    unsigned short o[8] = {f2bf(f0.x*zs), f2bf(f0.y*zs), f2bf(f0.z*zs), f2bf(f0.w*zs),
                           f2bf(f1.x*zs), f2bf(f1.y*zs), f2bf(f1.z*zs), f2bf(f1.w*zs)};
    const int kdst = (g >> 3) * 64 + (((g & 7) ^ (n & 7)) * 8);
    *(uint4*)(dst + (long)widx * NW_ + (long)n * D_ + kdst) = *(const uint4*)o;
}

// ---------------------------------------------------------------------------
// Activation cvt fp32 -> bf16, same xor swizzle (row key = n&7).
// ---------------------------------------------------------------------------
__global__ __launch_bounds__(256) void cvt_x(const float* __restrict__ xq,
                                             const float* __restrict__ xk,
                                             const float* __restrict__ xv,
                                             unsigned short* __restrict__ dst) {
    const float* src[3] = {xq, xk, xv};
    const int ten = blockIdx.y;
    const int idx = blockIdx.x * 256 + threadIdx.x;    // 393216 per tensor
    const int n = idx / 96;
    const int g = idx % 96;
    const float4 f0 = *(const float4*)(src[ten] + (long)n * D_ + g * 8);
    const float4 f1 = *(const float4*)(src[ten] + (long)n * D_ + g * 8 + 4);
    unsigned short o[8] = {f2bf(f0.x), f2bf(f0.y), f2bf(f0.z), f2bf(f0.w),
                           f2bf(f1.x), f2bf(f1.y), f2bf(f1.z), f2bf(f1.w)};
    const int kdst = (g >> 3) * 64 + (((g & 7) ^ (n & 7)) * 8);
    *(uint4*)(dst + (long)ten * NX_ + (long)n * D_ + kdst) = *(const uint4*)o;
}

// ---------------------------------------------------------------------------
// Fused QKV projection. grid(32, 18): y -> zz = y/6, nb = y%6. Tile 128x128,
// BK=64, 4 waves 2x2 (wave 64x64). BOTH operands async-staged from swizzled
// bf16 global. Outputs: Q/K [bh][s][dk]; V transposed+pi-permuted [bh][dk][s'].
// ---------------------------------------------------------------------------
struct QkvArgs { const float* bias[3]; unsigned short* out[3]; };

__global__ __launch_bounds__(256, 2) void gemm_qkv(QkvArgs args,
                                                   const unsigned short* __restrict__ Xsw,
                                                   const unsigned short* __restrict__ Wsw) {
    __shared__ __align__(16) unsigned short smem[17408];
    unsigned short* As = smem;           // [128][64] swizzled
    unsigned short* Bs = smem + 8192;    // [128][64] swizzled

    const int t    = threadIdx.x;
    const int wave = t >> 6;
    const int lane = t & 63;
    const int l16  = lane & 15;
    const int quad = lane >> 4;
    const int wm   = wave >> 1, wn = wave & 1;
    const int m0   = blockIdx.x * 128;
    const int zz   = blockIdx.y / 6;
    const int nb   = blockIdx.y % 6;
    const int n0   = nb * 128;

    const unsigned short* Ap = Xsw + (long)zz * NX_;
    const unsigned short* Wp = Wsw + (long)zz * NW_;

    f32x4 acc[4][4];
#pragma unroll
    for (int s = 0; s < 4; s++)
#pragma unroll
        for (int j = 0; j < 4; j++) acc[s][j] = (f32x4){0.f, 0.f, 0.f, 0.f};

    const int lrow = lane >> 3;          // row within 8-row chunk
    const int lcg  = lane & 7;           // 8-el group

    for (int k0 = 0; k0 < D_; k0 += 64) {
        __syncthreads();
#pragma unroll
        for (int i = 0; i < 4; i++) {    // A: 16 chunks, 4 per wave
            const int chunk = wave * 4 + i;
            async_cp16(Ap + (long)(m0 + chunk * 8 + lrow) * D_ + k0 + lcg * 8,
                       As + chunk * 512);
        }
#pragma unroll
        for (int i = 0; i < 4; i++) {    // B: 16 chunks, 4 per wave
            const int chunk = wave * 4 + i;
            async_cp16(Wp + (long)(n0 + chunk * 8 + lrow) * D_ + k0 + lcg * 8,
                       Bs + chunk * 512);
        }
        __syncthreads();
#pragma unroll
        for (int ks = 0; ks < 2; ks++) {
            const int cg = ks * 4 + quad;
            bf16x8 af[4], bf[4];
#pragma unroll
            for (int s = 0; s < 4; s++) {
                const int r = wm * 64 + s * 16 + l16;
                af[s] = *(const bf16x8*)&As[r * 64 + ((cg ^ (r & 7)) * 8)];
            }
#pragma unroll
            for (int j = 0; j < 4; j++) {
                const int r = wn * 64 + j * 16 + l16;
                bf[j] = *(const bf16x8*)&Bs[r * 64 + ((cg ^ (r & 7)) * 8)];
            }
#pragma unroll
            for (int s = 0; s < 4; s++)
#pragma unroll
                for (int j = 0; j < 4; j++)
                    acc[s][j] = __builtin_amdgcn_mfma_f32_16x16x32_bf16(af[s], bf[j], acc[s][j], 0, 0, 0);
        }
    }
    __syncthreads();

    const int b     = m0 >> 11;
    const int sbase = m0 & (S_ - 1);
    const float zs  = (zz == 0) ? CSC : 1.0f;   // bias scale matches wq scale
    float bv[4];
#pragma unroll
    for (int j = 0; j < 4; j++) bv[j] = args.bias[zz][n0 + wn * 64 + j * 16 + l16] * zs;

    if (zz < 2) {
        unsigned short* Ls = smem;       // [128][136]
#pragma unroll
        for (int s = 0; s < 4; s++)
#pragma unroll
            for (int j = 0; j < 4; j++)
#pragma unroll
                for (int r = 0; r < 4; r++)
                    Ls[(wm * 64 + s * 16 + quad * 4 + r) * 136 + wn * 64 + j * 16 + l16] =
                        f2bf(acc[s][j][r] + bv[j]);
        __syncthreads();
        const int row  = t >> 1;
        const int half = t & 1;
        unsigned short* Op = args.out[zz];
#pragma unroll
        for (int i = 0; i < 8; i++) {
            const int col  = half * 64 + i * 8;
            const int head = nb * 2 + half;
            const uint4 v = *(const uint4*)&Ls[row * 136 + col];
            *(uint4*)(Op + ((long)(b * H_ + head) * S_ + sbase + row) * DK_ + (col & 63)) = v;
        }
    } else {
        unsigned short* Ls = smem;       // [2][64][136]
#pragma unroll
        for (int s = 0; s < 4; s++)
#pragma unroll
            for (int j = 0; j < 4; j++)
#pragma unroll
                for (int r = 0; r < 4; r++) {
                    const int dk  = j * 16 + l16;
                    const int pos = wm * 64 + (quad * 4 + r) * 4 + s;   // pi-permute
                    Ls[wn * 8704 + dk * 136 + pos] = f2bf(acc[s][j][r] + bv[j]);
                }
        __syncthreads();
        const int rowIdx = t >> 1;
        const int hh = rowIdx >> 6, dk = rowIdx & 63;
        const int half = t & 1;
        unsigned short* Op = args.out[2];
#pragma unroll
        for (int i = 0; i < 8; i++) {
            const int col = half * 64 + i * 8;
            const uint4 v = *(const uint4*)&Ls[hh * 8704 + dk * 136 + col];
            const int head = nb * 2 + hh;
            *(uint4*)(Op + ((long)(b * H_ + head) * DK_ + dk) * S_ + sbase + col) = v;
        }
    }
}

// ---------------------------------------------------------------------------
// Flash attention, no-max softmax (Q pre-scaled so p = exp2(s) directly).
// Q,K [bh][s][dk] bf16; Vt [bh][dk][s'] pi-permuted. KV-split grid.z.
// fp32 partials written via LDS-vectorized epilogue (dwordx4, no write amp).
// ---------------------------------------------------------------------------
__global__ __launch_bounds__(256, 3) void attn_kernel(
    const unsigned short* __restrict__ Q, const unsigned short* __restrict__ K,
    const unsigned short* __restrict__ Vt,
    float* __restrict__ Opart, float* __restrict__ Lp,
    unsigned short* __restrict__ Ao, int kvlen, int direct)
{
    const int t    = threadIdx.x;
    const int wave = t >> 6;
    const int lane = t & 63;
    const int l16  = lane & 15;
    const int quad = lane >> 4;
    const int qtile = blockIdx.x;
    const int bh    = blockIdx.y;
    const int z     = blockIdx.z;
    const int kvbase = z * kvlen;
    const int NIT    = kvlen >> 6;

    const unsigned short* Qp = Q  + (long)bh * S_ * DK_;
    const unsigned short* Kp = K  + (long)bh * S_ * DK_;
    const unsigned short* Vp = Vt + (long)bh * DK_ * S_;

    __shared__ __align__(16) unsigned short smem[18432];
    unsigned short* Ks = smem;             // [64][72]
    unsigned short* Vs = smem + 4608;      // [64][72]  pi-permuted kv
    unsigned short* Ps = smem + 9216;      // [128][72] pi-permuted kv

    bf16x8 qfrag[2][2];
#pragma unroll
    for (int st = 0; st < 2; st++) {
        const long qoff = (long)(qtile * 128 + wave * 32 + st * 16 + l16) * DK_ + quad * 8;
        qfrag[st][0] = *(const bf16x8*)(Qp + qoff);
        qfrag[st][1] = *(const bf16x8*)(Qp + qoff + 32);
    }

    const int srow = t >> 2;            // 0..63
    const int scg  = (t & 3) * 16;
    uint4 kreg[2], vreg[2];
    {
        const unsigned short* gk = Kp + (long)(kvbase + srow) * DK_ + scg;
        const unsigned short* gv = Vp + (long)srow * S_ + kvbase + scg;
        kreg[0] = *(const uint4*)gk;  kreg[1] = *(const uint4*)(gk + 8);
        vreg[0] = *(const uint4*)gv;  vreg[1] = *(const uint4*)(gv + 8);
    }

    f32x4 oacc[2][4];
#pragma unroll
    for (int st = 0; st < 2; st++)
#pragma unroll
        for (int j = 0; j < 4; j++) oacc[st][j] = (f32x4){0.f, 0.f, 0.f, 0.f};
    float lsum[2][4] = {{0.f,0.f,0.f,0.f},{0.f,0.f,0.f,0.f}};

    for (int it = 0; it < NIT; ++it) {
        __syncthreads();
        *(uint4*)&Ks[srow * 72 + scg]     = kreg[0];
        *(uint4*)&Ks[srow * 72 + scg + 8] = kreg[1];
        *(uint4*)&Vs[srow * 72 + scg]     = vreg[0];
        *(uint4*)&Vs[srow * 72 + scg + 8] = vreg[1];
        __syncthreads();
        if (it + 1 < NIT) {
            const int kv0 = kvbase + (it + 1) * 64;
            const unsigned short* gk = Kp + (long)(kv0 + srow) * DK_ + scg;
            const unsigned short* gv = Vp + (long)srow * S_ + kv0 + scg;
            kreg[0] = *(const uint4*)gk;  kreg[1] = *(const uint4*)(gk + 8);
            vreg[0] = *(const uint4*)gv;  vreg[1] = *(const uint4*)(gv + 8);
        }

        f32x4 sacc[2][4];
#pragma unroll
        for (int st = 0; st < 2; st++)
#pragma unroll
            for (int j = 0; j < 4; j++) sacc[st][j] = (f32x4){0.f, 0.f, 0.f, 0.f};
#pragma unroll
        for (int ks = 0; ks < 2; ks++)
#pragma unroll
            for (int j = 0; j < 4; j++) {
                const bf16x8 bf = *(const bf16x8*)&Ks[(j * 16 + l16) * 72 + ks * 32 + quad * 8];
#pragma unroll
                for (int st = 0; st < 2; st++)
                    sacc[st][j] = __builtin_amdgcn_mfma_f32_16x16x32_bf16(qfrag[st][ks], bf, sacc[st][j], 0, 0, 0);
            }

        // p = exp2(s) (scale pre-baked); packed b64 P-stores, pi-permuted cols
#pragma unroll
        for (int st = 0; st < 2; st++)
#pragma unroll
            for (int r = 0; r < 4; r++) {
                float p0 = exp2f(sacc[st][0][r]);
                float p1 = exp2f(sacc[st][1][r]);
                float p2 = exp2f(sacc[st][2][r]);
                float p3 = exp2f(sacc[st][3][r]);
                lsum[st][r] += (p0 + p1) + (p2 + p3);
                uint2 pk = {pack_bf2(p0, p1), pack_bf2(p2, p3)};
                const int row = wave * 32 + st * 16 + quad * 4 + r;
                *(uint2*)&Ps[row * 72 + l16 * 4] = pk;
            }

#pragma unroll
        for (int st = 0; st < 2; st++)
#pragma unroll
            for (int ks = 0; ks < 2; ks++) {
                const bf16x8 pf = *(const bf16x8*)&Ps[(wave * 32 + st * 16 + l16) * 72 + ks * 32 + quad * 8];
#pragma unroll
                for (int j = 0; j < 4; j++) {
                    const bf16x8 vf = *(const bf16x8*)&Vs[(j * 16 + l16) * 72 + ks * 32 + quad * 8];
                    oacc[st][j] = __builtin_amdgcn_mfma_f32_16x16x32_bf16(pf, vf, oacc[st][j], 0, 0, 0);
                }
            }
    }

#pragma unroll
    for (int st = 0; st < 2; st++)
#pragma unroll
        for (int r = 0; r < 4; r++)
#pragma unroll
            for (int off = 1; off < 16; off <<= 1)
                lsum[st][r] += __shfl_xor(lsum[st][r], off, 64);

    if (direct) {
        const int b = bh / H_, h = bh % H_;
#pragma unroll
        for (int st = 0; st < 2; st++)
#pragma unroll
            for (int r = 0; r < 4; r++) {
                const float inv = 1.f / lsum[st][r];
                const int qrow = qtile * 128 + wave * 32 + st * 16 + quad * 4 + r;
#pragma unroll
                for (int j = 0; j < 4; j++) {
                    const int dk = j * 16 + l16;
                    const int dkw = ((dk >> 3) ^ (qrow & 7)) * 8 + (dk & 7);  // swizzled
                    Ao[(long)(b * S_ + qrow) * D_ + h * DK_ + dkw] =
                        f2bf(oacc[st][j][r] * inv);
                }
            }
    } else {
        float* Lq = Lp + (long)z * NR_ + (long)bh * S_ + qtile * 128;
#pragma unroll
        for (int st = 0; st < 2; st++)
#pragma unroll
            for (int r = 0; r < 4; r++) {
                const int row = wave * 32 + st * 16 + quad * 4 + r;
                if (l16 == 0) Lq[row] = lsum[st][r];
            }
        // vectorized fp32 partial write via LDS
        __syncthreads();
        float* fl = (float*)smem;        // [128][67]
#pragma unroll
        for (int st = 0; st < 2; st++)
#pragma unroll
            for (int j = 0; j < 4; j++)
#pragma unroll
                for (int r = 0; r < 4; r++)
                    fl[(wave * 32 + st * 16 + quad * 4 + r) * 67 + j * 16 + l16] = oacc[st][j][r];
        __syncthreads();
        float* Op = Opart + (long)z * NX_ + (long)bh * S_ * DK_ + (long)qtile * 128 * DK_;
        const int row = t >> 1, c0 = (t & 1) * 32;
#pragma unroll
        for (int i = 0; i < 8; i++) {
            const float4 v = *(const float4*)&fl[row * 67 + c0 + i * 4];
            *(float4*)(Op + row * DK_ + c0 + i * 4) = v;
        }
    }
}

// ---------------------------------------------------------------------------
// Combine KV-split partials -> Ao bf16 [b][s][D], xor-swizzled per 64-block.
// ---------------------------------------------------------------------------
__global__ __launch_bounds__(256) void combine_kernel(
    const float* __restrict__ Opart, const float* __restrict__ Lp,
    unsigned short* __restrict__ Ao)
{
    const long i = ((long)blockIdx.x * 256 + threadIdx.x) * 8;   // [bh][s][dk] flat
    const int row = (int)(i >> 6);
    const float inv = 1.f / (Lp[row] + Lp[NR_ + row]);
    const float4 a0 = *(const float4*)(Opart + i);
    const float4 a1 = *(const float4*)(Opart + i + 4);
    const float4 b0 = *(const float4*)(Opart + NX_ + i);
    const float4 b1 = *(const float4*)(Opart + NX_ + i + 4);
    unsigned short o[8] = {
        f2bf((a0.x + b0.x) * inv), f2bf((a0.y + b0.y) * inv),
        f2bf((a0.z + b0.z) * inv), f2bf((a0.w + b0.w) * inv),
        f2bf((a1.x + b1.x) * inv), f2bf((a1.y + b1.y) * inv),
        f2bf((a1.z + b1.z) * inv), f2bf((a1.w + b1.w) * inv)};
    const int bh = row >> 11, s = row & (S_ - 1);
    const int b = bh / H_, h = bh % H_;
    const int g8 = (int)(i & 63) >> 3;
    const int dkw = ((g8 ^ (s & 7)) * 8);
    *(uint4*)(Ao + (long)(b * S_ + s) * D_ + h * DK_ + dkw) = *(const uint4*)o;
}

// ---------------------------------------------------------------------------
// Output projection: Ao_sw bf16 @ Wo_sw -> fp32 d_out. Tile 128x128, both
// operands async. fp32 out via 2-pass LDS-vectorized epilogue. grid (32,6).
// ---------------------------------------------------------------------------
__global__ __launch_bounds__(256, 2) void gemm_out(
    const unsigned short* __restrict__ A, const unsigned short* __restrict__ Wsw,
    const float* __restrict__ bias, float* __restrict__ Out)
{
    __shared__ __align__(16) unsigned short smem[17408];
    unsigned short* As = smem;
    unsigned short* Bs = smem + 8192;

    const int t    = threadIdx.x;
    const int wave = t >> 6;
    const int lane = t & 63;
    const int l16  = lane & 15;
    const int quad = lane >> 4;
    const int wm   = wave >> 1, wn = wave & 1;
    const int m0   = blockIdx.x * 128;
    const int n0   = blockIdx.y * 128;

    f32x4 acc[4][4];
#pragma unroll
    for (int s = 0; s < 4; s++)
#pragma unroll
        for (int j = 0; j < 4; j++) acc[s][j] = (f32x4){0.f, 0.f, 0.f, 0.f};

    const int lrow = lane >> 3;
    const int lcg  = lane & 7;

    for (int k0 = 0; k0 < D_; k0 += 64) {
        __syncthreads();
#pragma unroll
        for (int i = 0; i < 4; i++) {
            const int chunk = wave * 4 + i;
            async_cp16(A + (long)(m0 + chunk * 8 + lrow) * D_ + k0 + lcg * 8,
                       As + chunk * 512);
        }
#pragma unroll
        for (int i = 0; i < 4; i++) {
            const int chunk = wave * 4 + i;
            async_cp16(Wsw + (long)(n0 + chunk * 8 + lrow) * D_ + k0 + lcg * 8,
                       Bs + chunk * 512);
        }
        __syncthreads();
#pragma unroll
        for (int ks = 0; ks < 2; ks++) {
            const int cg = ks * 4 + quad;
            bf16x8 af[4], bf[4];
#pragma unroll
            for (int s = 0; s < 4; s++) {
                const int r = wm * 64 + s * 16 + l16;
                af[s] = *(const bf16x8*)&As[r * 64 + ((cg ^ (r & 7)) * 8)];
            }
#pragma unroll
            for (int j = 0; j < 4; j++) {
                const int r = wn * 64 + j * 16 + l16;
                bf[j] = *(const bf16x8*)&Bs[r * 64 + ((cg ^ (r & 7)) * 8)];
            }
#pragma unroll
            for (int s = 0; s < 4; s++)
#pragma unroll
                for (int j = 0; j < 4; j++)
                    acc[s][j] = __builtin_amdgcn_mfma_f32_16x16x32_bf16(af[s], bf[j], acc[s][j], 0, 0, 0);
        }
    }

    float bv[4];
#pragma unroll
    for (int j = 0; j < 4; j++) bv[j] = bias[n0 + wn * 64 + j * 16 + l16];

    float* fl = (float*)smem;            // [128][67]
#pragma unroll
    for (int h = 0; h < 2; h++) {        // n-half passes
        __syncthreads();
        if (wn == h) {
#pragma unroll
            for (int s = 0; s < 4; s++)
#pragma unroll
                for (int j = 0; j < 4; j++)
#pragma unroll
                    for (int r = 0; r < 4; r++)
                        fl[(wm * 64 + s * 16 + quad * 4 + r) * 67 + j * 16 + l16] =
                            acc[s][j][r] + bv[j];
        }
        __syncthreads();
        const int row = t >> 1, c0 = (t & 1) * 32;
#pragma unroll
        for (int i = 0; i < 8; i++) {
            const float4 v = *(const float4*)&fl[row * 67 + c0 + i * 4];
            *(float4*)(Out + (long)(m0 + row) * D_ + n0 + h * 64 + c0 + i * 4) = v;
        }
    }
}

extern "C" void kernel_launch(void* const* d_in, const int* in_sizes, int n_in,
                              void* d_out, int out_size, void* d_ws, size_t ws_size,
                              hipStream_t stream) {
    const float* k_in = (const float*)d_in[0];
    const float* q_in = (const float*)d_in[1];
    const float* v_in = (const float*)d_in[2];
    // d_in[3] = mask: no-op per reference
    const float* wq = (const float*)d_in[4];
    const float* bq = (const float*)d_in[5];
    const float* wk = (const float*)d_in[6];
    const float* bk = (const float*)d_in[7];
    const float* wv = (const float*)d_in[8];
    const float* bv = (const float*)d_in[9];
    const float* wo = (const float*)d_in[10];
    const float* bo = (const float*)d_in[11];

    unsigned short* ws = (unsigned short*)d_ws;
    unsigned short* Wsw = ws;                          // 4*NW bf16 swizzled
    unsigned short* Qb  = Wsw + 4ll * NW_;             // NX bf16
    unsigned short* Kb  = Qb + (long)NX_;
    unsigned short* Vt  = Kb + (long)NX_;
    unsigned short* Xsw = Vt + (long)NX_;              // 3*NX bf16 (dead after qkv)

    const size_t need_split = (4ull*NW_ + 3ull*NX_)*2 + 2ull*NX_*4 + 2ull*NR_*4;
    const bool split = ws_size >= need_split;

    float* Opart = (float*)Xsw;                        // aliases Xsw (+ tail)
    float* Lp    = Opart + 2ll * NX_;
    unsigned short* Ao = split ? Qb                    // Qb dead after attn
                               : Xsw;                  // Xsw dead after qkv

    cvt_w<<<dim3(288, 4), 256, 0, stream>>>(wq, wk, wv, wo, Wsw);
    cvt_x<<<dim3(1536, 3), 256, 0, stream>>>(q_in, k_in, v_in, Xsw);

    QkvArgs qa;
    qa.bias[0] = bq; qa.bias[1] = bk; qa.bias[2] = bv;
    qa.out[0] = Qb;  qa.out[1] = Kb;  qa.out[2] = Vt;
    gemm_qkv<<<dim3(32, 18), 256, 0, stream>>>(qa, Xsw, Wsw);

    if (split) {
        attn_kernel<<<dim3(S_/128, B_*H_, 2), 256, 0, stream>>>(
            Qb, Kb, Vt, Opart, Lp, nullptr, S_/2, 0);
        combine_kernel<<<dim3(NX_/2048), 256, 0, stream>>>(Opart, Lp, Ao);
    } else {
        attn_kernel<<<dim3(S_/128, B_*H_, 1), 256, 0, stream>>>(
            Qb, Kb, Vt, nullptr, nullptr, Ao, S_, 1);
    }

    gemm_out<<<dim3(32, 6), 256, 0, stream>>>(Ao, Wsw + 3ll*NW_, bo, (float*)d_out);
}